// Round 1
// baseline (630.385 us; speedup 1.0000x reference)
//
#include <hip/hip_runtime.h>
#include <math.h>

// ---------------------------------------------------------------------------
// GCN: out = relu(Ahat @ (relu(Ahat @ (x@W1)+b1) @ W2)+b2) @ Wl + bl
// Ahat = D^-1/2 (A+I) D^-1/2, deg from dst (in-degree incl. self-loop).
// ---------------------------------------------------------------------------

__global__ void k_deg_init(float* deg, int n) {
    int i = blockIdx.x * blockDim.x + threadIdx.x;
    if (i < n) deg[i] = 1.0f;   // self-loop
}

__global__ void k_deg_count(const int* __restrict__ dst, float* deg, int E) {
    int e = blockIdx.x * blockDim.x + threadIdx.x;
    if (e < E) atomicAdd(&deg[dst[e]], 1.0f);
}

__global__ void k_rsqrt(float* deg, int n) {
    int i = blockIdx.x * blockDim.x + threadIdx.x;
    if (i < n) deg[i] = rsqrtf(deg[i]);
}

// Dense GEMM: [n,64] @ [64,F].  64 rows per block, 256 threads,
// each thread computes a 4-row x (F/16)-col register tile.
// Non-FINAL: writes t_out = in@W and agg_out = bias + dinv^2 * t (self-loop init).
// FINAL:     writes t_out = in@W + bias  (the classifier head).
template <int F, bool RELU_IN, bool FINAL>
__launch_bounds__(256)
__global__ void k_mm(const float* __restrict__ in, const float* __restrict__ W,
                     const float* __restrict__ bias, const float* __restrict__ dinv,
                     float* __restrict__ t_out, float* __restrict__ agg_out, int n) {
    __shared__ float in_s[64 * 68];   // 64 rows, stride 68 (bank-conflict pad)
    __shared__ float w_s[64 * F];

    const int tid  = threadIdx.x;
    const int row0 = blockIdx.x * 64;

    // stage W (64*F floats) as float4
    for (int i4 = tid; i4 < (64 * F) / 4; i4 += 256)
        ((float4*)w_s)[i4] = ((const float4*)W)[i4];

    // stage 64 input rows (64 floats each) as float4, optional relu
    for (int idx = tid; idx < 64 * 16; idx += 256) {
        int r  = idx >> 4;
        int c4 = idx & 15;
        float4 v;
        if (row0 + r < n)
            v = *(const float4*)&in[(size_t)(row0 + r) * 64 + c4 * 4];
        else
            v = make_float4(0.f, 0.f, 0.f, 0.f);
        if (RELU_IN) {
            v.x = fmaxf(v.x, 0.f); v.y = fmaxf(v.y, 0.f);
            v.z = fmaxf(v.z, 0.f); v.w = fmaxf(v.w, 0.f);
        }
        *(float4*)&in_s[r * 68 + c4 * 4] = v;
    }
    __syncthreads();

    constexpr int CPT = F / 16;      // cols per thread (4 or 2)
    const int tx = tid & 15;         // col group
    const int ty = tid >> 4;         // row group (4 rows each)

    float acc[4][CPT];
#pragma unroll
    for (int r = 0; r < 4; ++r)
#pragma unroll
        for (int c = 0; c < CPT; ++c) acc[r][c] = 0.f;

#pragma unroll 4
    for (int k = 0; k < 64; ++k) {
        float b[CPT];
#pragma unroll
        for (int c = 0; c < CPT; ++c) b[c] = w_s[k * F + tx * CPT + c];
#pragma unroll
        for (int r = 0; r < 4; ++r) {
            float a = in_s[(ty * 4 + r) * 68 + k];
#pragma unroll
            for (int c = 0; c < CPT; ++c) acc[r][c] = fmaf(a, b[c], acc[r][c]);
        }
    }

#pragma unroll
    for (int r = 0; r < 4; ++r) {
        int row = row0 + ty * 4 + r;
        if (row >= n) continue;
        if constexpr (FINAL) {
#pragma unroll
            for (int c = 0; c < CPT; ++c) {
                int col = tx * CPT + c;
                t_out[(size_t)row * F + col] = acc[r][c] + bias[col];
            }
        } else {
            float di = dinv[row];
            float w2 = di * di;
#pragma unroll
            for (int c = 0; c < CPT; ++c) {
                int col = tx * CPT + c;
                float v = acc[r][c];
                t_out[(size_t)row * F + col]   = v;
                agg_out[(size_t)row * F + col] = bias[col] + w2 * v;
            }
        }
    }
}

// Edge aggregation: one wave (64 lanes) per edge, lane = feature.
// agg[dst][lane] += dinv[src]*dinv[dst] * t[src][lane]
__global__ void k_scatter(const int* __restrict__ src, const int* __restrict__ dst,
                          const float* __restrict__ dinv, const float* __restrict__ t,
                          float* agg, int E) {
    int e    = (int)((blockIdx.x * (size_t)blockDim.x + threadIdx.x) >> 6);
    int lane = threadIdx.x & 63;
    if (e < E) {
        int s = src[e], d = dst[e];
        float w = dinv[s] * dinv[d];
        atomicAdd(&agg[(size_t)d * 64 + lane], w * t[(size_t)s * 64 + lane]);
    }
}

extern "C" void kernel_launch(void* const* d_in, const int* in_sizes, int n_in,
                              void* d_out, int out_size, void* d_ws, size_t ws_size,
                              hipStream_t stream) {
    const float* x  = (const float*)d_in[0];
    const int*   ei = (const int*)d_in[1];
    const float* W1 = (const float*)d_in[2];
    const float* b1 = (const float*)d_in[3];
    const float* W2 = (const float*)d_in[4];
    const float* b2 = (const float*)d_in[5];
    const float* Wl = (const float*)d_in[6];
    const float* bl = (const float*)d_in[7];
    float*       out = (float*)d_out;

    const int N = in_sizes[0] / 64;
    const int E = in_sizes[1] / 2;
    const int* srcp = ei;
    const int* dstp = ei + E;

    char*  ws  = (char*)d_ws;
    size_t off = 0;
    auto alloc = [&](size_t bytes) -> float* {
        float* p = (float*)(ws + off);
        off += (bytes + 255) & ~(size_t)255;
        return p;
    };
    float* dinv = alloc((size_t)N * 4);
    float* t    = alloc((size_t)N * 64 * 4);
    float* agg1 = alloc((size_t)N * 64 * 4);
    float* agg2 = alloc((size_t)N * 64 * 4);

    const int nb_n  = (N + 255) / 256;
    const int nb_e  = (E + 255) / 256;
    const int nb_mm = (N + 63) / 64;
    const int nb_sc = (int)(((size_t)E * 64 + 255) / 256);

    // degree -> dinv
    k_deg_init<<<nb_n, 256, 0, stream>>>(dinv, N);
    k_deg_count<<<nb_e, 256, 0, stream>>>(dstp, dinv, E);
    k_rsqrt<<<nb_n, 256, 0, stream>>>(dinv, N);

    // layer 1
    k_mm<64, false, false><<<nb_mm, 256, 0, stream>>>(x, W1, b1, dinv, t, agg1, N);
    k_scatter<<<nb_sc, 256, 0, stream>>>(srcp, dstp, dinv, t, agg1, E);

    // layer 2 (relu on agg1 applied at load)
    k_mm<64, true, false><<<nb_mm, 256, 0, stream>>>(agg1, W2, b2, dinv, t, agg2, N);
    k_scatter<<<nb_sc, 256, 0, stream>>>(srcp, dstp, dinv, t, agg2, E);

    // classifier head (relu on agg2 applied at load)
    k_mm<32, true, true><<<nb_mm, 256, 0, stream>>>(agg2, Wl, bl, nullptr, out, nullptr, N);
}

// Round 2
// 369.697 us; speedup vs baseline: 1.7051x; 1.7051x over previous
//
#include <hip/hip_runtime.h>
#include <math.h>

// ---------------------------------------------------------------------------
// GCN via on-device CSR build + atomic-free gather aggregation.
// out = (relu(Ahat@(relu(Ahat@(x@W1)+b1))@W2+b2)) @ Wl + bl
// Ahat = D^-1/2 (A+I) D^-1/2, deg = in-degree(dst) + 1.
// ---------------------------------------------------------------------------

#define SCAN_TPB 256
#define SCAN_EPB 1024   // 256 threads * 4 elems

__global__ void k_zero_int(int* p, int n) {
    int i = blockIdx.x * blockDim.x + threadIdx.x;
    if (i < n) p[i] = 0;
}

__global__ void k_hist(const int* __restrict__ dst, int* cnt, int E) {
    int e = blockIdx.x * blockDim.x + threadIdx.x;
    if (e < E) atomicAdd(&cnt[dst[e]], 1);
}

// pass 1: per-block sums of cnt (1024 elems/block)
__global__ __launch_bounds__(SCAN_TPB)
void k_scan1(const int* __restrict__ cnt, int* bsum, int N) {
    __shared__ int s[SCAN_TPB];
    int tid = threadIdx.x;
    int i0  = blockIdx.x * SCAN_EPB + tid * 4;
    int t = 0;
#pragma unroll
    for (int k = 0; k < 4; ++k) {
        int i = i0 + k;
        t += (i < N) ? cnt[i] : 0;
    }
    s[tid] = t;
    __syncthreads();
    for (int off = SCAN_TPB / 2; off > 0; off >>= 1) {
        if (tid < off) s[tid] += s[tid + off];
        __syncthreads();
    }
    if (tid == 0) bsum[blockIdx.x] = s[0];
}

// pass 2: exclusive scan of block sums (single block), write total to row_ptr[N]
__global__ __launch_bounds__(SCAN_TPB)
void k_scan2(int* bsum, int* row_ptr, int NB, int N) {
    __shared__ int s[SCAN_TPB];
    int tid = threadIdx.x;
    int v = (tid < NB) ? bsum[tid] : 0;
    s[tid] = v;
    __syncthreads();
    for (int off = 1; off < SCAN_TPB; off <<= 1) {
        int x = (tid >= off) ? s[tid - off] : 0;
        __syncthreads();
        s[tid] += x;
        __syncthreads();
    }
    if (tid < NB) bsum[tid] = s[tid] - v;       // exclusive
    if (tid == SCAN_TPB - 1) row_ptr[N] = s[SCAN_TPB - 1];  // total = E
}

// pass 3: full exclusive scan -> row_ptr & cursor; also dinv = rsqrt(cnt+1)
__global__ __launch_bounds__(SCAN_TPB)
void k_scan3(const int* __restrict__ cnt, const int* __restrict__ bsum,
             int* row_ptr, int* cursor, float* dinv, int N) {
    __shared__ int s[SCAN_TPB];
    int tid = threadIdx.x;
    int i0  = blockIdx.x * SCAN_EPB + tid * 4;
    int v[4];
#pragma unroll
    for (int k = 0; k < 4; ++k) {
        int i = i0 + k;
        v[k] = (i < N) ? cnt[i] : 0;
    }
    int tsum = v[0] + v[1] + v[2] + v[3];
    s[tid] = tsum;
    __syncthreads();
    for (int off = 1; off < SCAN_TPB; off <<= 1) {
        int x = (tid >= off) ? s[tid - off] : 0;
        __syncthreads();
        s[tid] += x;
        __syncthreads();
    }
    int base = bsum[blockIdx.x] + (s[tid] - tsum);  // exclusive within grid
    int run = 0;
#pragma unroll
    for (int k = 0; k < 4; ++k) {
        int i = i0 + k;
        if (i < N) {
            row_ptr[i] = base + run;
            cursor[i]  = base + run;
            dinv[i]    = rsqrtf((float)(v[k] + 1));
        }
        run += v[k];
    }
}

// bucket fill: colw[p] = {src, dinv[src]*dinv[dst]}
__global__ void k_fill(const int* __restrict__ src, const int* __restrict__ dst,
                       const float* __restrict__ dinv, int* cursor,
                       int2* __restrict__ colw, int E) {
    int e = blockIdx.x * blockDim.x + threadIdx.x;
    if (e < E) {
        int s = src[e], d = dst[e];
        int p = atomicAdd(&cursor[d], 1);
        colw[p] = make_int2(s, __float_as_int(dinv[s] * dinv[d]));
    }
}

// Dense GEMM: [n,64] @ [64,F], writes t_out = in@W (+bias if FINAL).
template <int F, bool FINAL>
__launch_bounds__(256)
__global__ void k_mm(const float* __restrict__ in, const float* __restrict__ W,
                     const float* __restrict__ bias,
                     float* __restrict__ t_out, int n) {
    __shared__ float in_s[64 * 68];
    __shared__ float w_s[64 * F];

    const int tid  = threadIdx.x;
    const int row0 = blockIdx.x * 64;

    for (int i4 = tid; i4 < (64 * F) / 4; i4 += 256)
        ((float4*)w_s)[i4] = ((const float4*)W)[i4];

    for (int idx = tid; idx < 64 * 16; idx += 256) {
        int r  = idx >> 4;
        int c4 = idx & 15;
        float4 v;
        if (row0 + r < n)
            v = *(const float4*)&in[(size_t)(row0 + r) * 64 + c4 * 4];
        else
            v = make_float4(0.f, 0.f, 0.f, 0.f);
        *(float4*)&in_s[r * 68 + c4 * 4] = v;
    }
    __syncthreads();

    constexpr int CPT = F / 16;
    const int tx = tid & 15;
    const int ty = tid >> 4;

    float acc[4][CPT];
#pragma unroll
    for (int r = 0; r < 4; ++r)
#pragma unroll
        for (int c = 0; c < CPT; ++c) acc[r][c] = 0.f;

#pragma unroll 4
    for (int k = 0; k < 64; ++k) {
        float b[CPT];
#pragma unroll
        for (int c = 0; c < CPT; ++c) b[c] = w_s[k * F + tx * CPT + c];
#pragma unroll
        for (int r = 0; r < 4; ++r) {
            float a = in_s[(ty * 4 + r) * 68 + k];
#pragma unroll
            for (int c = 0; c < CPT; ++c) acc[r][c] = fmaf(a, b[c], acc[r][c]);
        }
    }

#pragma unroll
    for (int r = 0; r < 4; ++r) {
        int row = row0 + ty * 4 + r;
        if (row >= n) continue;
#pragma unroll
        for (int c = 0; c < CPT; ++c) {
            int col = tx * CPT + c;
            float v = acc[r][c];
            if constexpr (FINAL) v += bias[col];
            t_out[(size_t)row * F + col] = v;
        }
    }
}

// Gather aggregation: one wave per dst node, lane = feature.
// agg[d] = relu(bias + dinv[d]^2 * t[d] + sum_e w_e * t[src_e])
__global__ __launch_bounds__(256)
void k_gather(const int* __restrict__ row_ptr, const int2* __restrict__ colw,
              const float* __restrict__ dinv, const float* __restrict__ bias,
              const float* __restrict__ t, float* __restrict__ agg, int N) {
    int gid  = blockIdx.x * blockDim.x + threadIdx.x;
    int d    = gid >> 6;
    int lane = threadIdx.x & 63;
    if (d >= N) return;

    int beg = row_ptr[d], end = row_ptr[d + 1];
    float dd  = dinv[d];
    float acc = bias[lane] + dd * dd * t[(size_t)d * 64 + lane];

    for (int base = beg; base < end; base += 64) {
        int nc = end - base;
        if (nc > 64) nc = 64;
        int2 cw = (lane < nc) ? colw[base + lane] : make_int2(0, 0);
        for (int j = 0; j < nc; ++j) {
            int   sj = __shfl(cw.x, j);
            float wj = __int_as_float(__shfl(cw.y, j));
            acc = fmaf(wj, t[(size_t)sj * 64 + lane], acc);
        }
    }
    agg[(size_t)d * 64 + lane] = fmaxf(acc, 0.f);
}

extern "C" void kernel_launch(void* const* d_in, const int* in_sizes, int n_in,
                              void* d_out, int out_size, void* d_ws, size_t ws_size,
                              hipStream_t stream) {
    const float* x  = (const float*)d_in[0];
    const int*   ei = (const int*)d_in[1];
    const float* W1 = (const float*)d_in[2];
    const float* b1 = (const float*)d_in[3];
    const float* W2 = (const float*)d_in[4];
    const float* b2 = (const float*)d_in[5];
    const float* Wl = (const float*)d_in[6];
    const float* bl = (const float*)d_in[7];
    float*       out = (float*)d_out;

    const int N = in_sizes[0] / 64;
    const int E = in_sizes[1] / 2;
    const int* srcp = ei;
    const int* dstp = ei + E;

    char*  ws  = (char*)d_ws;
    size_t off = 0;
    auto alloc = [&](size_t bytes) -> void* {
        void* p = (void*)(ws + off);
        off += (bytes + 255) & ~(size_t)255;
        return p;
    };
    const int NB = (N + SCAN_EPB - 1) / SCAN_EPB;

    int*   cnt     = (int*)alloc((size_t)N * 4);
    int*   row_ptr = (int*)alloc((size_t)(N + 1) * 4);
    int*   cursor  = (int*)alloc((size_t)N * 4);
    int*   bsum    = (int*)alloc((size_t)NB * 4);
    float* dinv    = (float*)alloc((size_t)N * 4);
    int2*  colw    = (int2*)alloc((size_t)E * 8);
    float* t       = (float*)alloc((size_t)N * 64 * 4);
    float* agg1    = (float*)alloc((size_t)N * 64 * 4);
    float* agg2    = agg1;   // safe: agg1 dead once mm2 wrote t

    const int nb_n  = (N + 255) / 256;
    const int nb_e  = (E + 255) / 256;
    const int nb_mm = (N + 63) / 64;
    const int nb_g  = (int)(((size_t)N * 64 + 255) / 256);

    // --- CSR build ---
    k_zero_int<<<nb_n, 256, 0, stream>>>(cnt, N);
    k_hist<<<nb_e, 256, 0, stream>>>(dstp, cnt, E);
    k_scan1<<<NB, SCAN_TPB, 0, stream>>>(cnt, bsum, N);
    k_scan2<<<1, SCAN_TPB, 0, stream>>>(bsum, row_ptr, NB, N);
    k_scan3<<<NB, SCAN_TPB, 0, stream>>>(cnt, bsum, row_ptr, cursor, dinv, N);
    k_fill<<<nb_e, 256, 0, stream>>>(srcp, dstp, dinv, cursor, colw, E);

    // --- layer 1 ---
    k_mm<64, false><<<nb_mm, 256, 0, stream>>>(x, W1, nullptr, t, N);
    k_gather<<<nb_g, 256, 0, stream>>>(row_ptr, colw, dinv, b1, t, agg1, N);

    // --- layer 2 ---
    k_mm<64, false><<<nb_mm, 256, 0, stream>>>(agg1, W2, nullptr, t, N);
    k_gather<<<nb_g, 256, 0, stream>>>(row_ptr, colw, dinv, b2, t, agg2, N);

    // --- head ---
    k_mm<32, true><<<nb_mm, 256, 0, stream>>>(agg2, Wl, bl, out, N);
}

// Round 3
// 315.422 us; speedup vs baseline: 1.9985x; 1.1721x over previous
//
#include <hip/hip_runtime.h>
#include <math.h>

// ---------------------------------------------------------------------------
// GCN via on-device CSR build + atomic-free gather aggregation (MLP-unrolled).
// out = (relu(Ahat@(relu(Ahat@(x@W1)+b1))@W2+b2)) @ Wl + bl
// Ahat = D^-1/2 (A+I) D^-1/2, deg = in-degree(dst) + 1.
// ---------------------------------------------------------------------------

#define SCAN_TPB 256
#define SCAN_EPB 1024   // 256 threads * 4 elems

__global__ void k_zero_int(int* p, int n) {
    int i = blockIdx.x * blockDim.x + threadIdx.x;
    if (i < n) p[i] = 0;
}

__global__ void k_hist(const int* __restrict__ dst, int* cnt, int E) {
    int e = blockIdx.x * blockDim.x + threadIdx.x;
    if (e < E) atomicAdd(&cnt[dst[e]], 1);
}

// pass 1: per-block sums of cnt (1024 elems/block)
__global__ __launch_bounds__(SCAN_TPB)
void k_scan1(const int* __restrict__ cnt, int* bsum, int N) {
    __shared__ int s[SCAN_TPB];
    int tid = threadIdx.x;
    int i0  = blockIdx.x * SCAN_EPB + tid * 4;
    int t = 0;
#pragma unroll
    for (int k = 0; k < 4; ++k) {
        int i = i0 + k;
        t += (i < N) ? cnt[i] : 0;
    }
    s[tid] = t;
    __syncthreads();
    for (int off = SCAN_TPB / 2; off > 0; off >>= 1) {
        if (tid < off) s[tid] += s[tid + off];
        __syncthreads();
    }
    if (tid == 0) bsum[blockIdx.x] = s[0];
}

// pass 2: exclusive scan of block sums (single block), write total to row_ptr[N]
__global__ __launch_bounds__(SCAN_TPB)
void k_scan2(int* bsum, int* row_ptr, int NB, int N) {
    __shared__ int s[SCAN_TPB];
    int tid = threadIdx.x;
    int v = (tid < NB) ? bsum[tid] : 0;
    s[tid] = v;
    __syncthreads();
    for (int off = 1; off < SCAN_TPB; off <<= 1) {
        int x = (tid >= off) ? s[tid - off] : 0;
        __syncthreads();
        s[tid] += x;
        __syncthreads();
    }
    if (tid < NB) bsum[tid] = s[tid] - v;       // exclusive
    if (tid == SCAN_TPB - 1) row_ptr[N] = s[SCAN_TPB - 1];  // total = E
}

// pass 3: full exclusive scan -> row_ptr & cursor; also dinv = rsqrt(cnt+1)
__global__ __launch_bounds__(SCAN_TPB)
void k_scan3(const int* __restrict__ cnt, const int* __restrict__ bsum,
             int* row_ptr, int* cursor, float* dinv, int N) {
    __shared__ int s[SCAN_TPB];
    int tid = threadIdx.x;
    int i0  = blockIdx.x * SCAN_EPB + tid * 4;
    int v[4];
#pragma unroll
    for (int k = 0; k < 4; ++k) {
        int i = i0 + k;
        v[k] = (i < N) ? cnt[i] : 0;
    }
    int tsum = v[0] + v[1] + v[2] + v[3];
    s[tid] = tsum;
    __syncthreads();
    for (int off = 1; off < SCAN_TPB; off <<= 1) {
        int x = (tid >= off) ? s[tid - off] : 0;
        __syncthreads();
        s[tid] += x;
        __syncthreads();
    }
    int base = bsum[blockIdx.x] + (s[tid] - tsum);  // exclusive within grid
    int run = 0;
#pragma unroll
    for (int k = 0; k < 4; ++k) {
        int i = i0 + k;
        if (i < N) {
            row_ptr[i] = base + run;
            cursor[i]  = base + run;
            dinv[i]    = rsqrtf((float)(v[k] + 1));
        }
        run += v[k];
    }
}

// bucket fill: colw[p] = {src, dinv[src]*dinv[dst]}
__global__ void k_fill(const int* __restrict__ src, const int* __restrict__ dst,
                       const float* __restrict__ dinv, int* cursor,
                       int2* __restrict__ colw, int E) {
    int e = blockIdx.x * blockDim.x + threadIdx.x;
    if (e < E) {
        int s = src[e], d = dst[e];
        int p = atomicAdd(&cursor[d], 1);
        colw[p] = make_int2(s, __float_as_int(dinv[s] * dinv[d]));
    }
}

// Dense GEMM: [n,64] @ [64,F], writes t_out = in@W (+bias if FINAL).
template <int F, bool FINAL>
__launch_bounds__(256)
__global__ void k_mm(const float* __restrict__ in, const float* __restrict__ W,
                     const float* __restrict__ bias,
                     float* __restrict__ t_out, int n) {
    __shared__ float in_s[64 * 68];
    __shared__ float w_s[64 * F];

    const int tid  = threadIdx.x;
    const int row0 = blockIdx.x * 64;

    for (int i4 = tid; i4 < (64 * F) / 4; i4 += 256)
        ((float4*)w_s)[i4] = ((const float4*)W)[i4];

    for (int idx = tid; idx < 64 * 16; idx += 256) {
        int r  = idx >> 4;
        int c4 = idx & 15;
        float4 v;
        if (row0 + r < n)
            v = *(const float4*)&in[(size_t)(row0 + r) * 64 + c4 * 4];
        else
            v = make_float4(0.f, 0.f, 0.f, 0.f);
        *(float4*)&in_s[r * 68 + c4 * 4] = v;
    }
    __syncthreads();

    constexpr int CPT = F / 16;
    const int tx = tid & 15;
    const int ty = tid >> 4;

    float acc[4][CPT];
#pragma unroll
    for (int r = 0; r < 4; ++r)
#pragma unroll
        for (int c = 0; c < CPT; ++c) acc[r][c] = 0.f;

#pragma unroll 4
    for (int k = 0; k < 64; ++k) {
        float b[CPT];
#pragma unroll
        for (int c = 0; c < CPT; ++c) b[c] = w_s[k * F + tx * CPT + c];
#pragma unroll
        for (int r = 0; r < 4; ++r) {
            float a = in_s[(ty * 4 + r) * 68 + k];
#pragma unroll
            for (int c = 0; c < CPT; ++c) acc[r][c] = fmaf(a, b[c], acc[r][c]);
        }
    }

#pragma unroll
    for (int r = 0; r < 4; ++r) {
        int row = row0 + ty * 4 + r;
        if (row >= n) continue;
#pragma unroll
        for (int c = 0; c < CPT; ++c) {
            int col = tx * CPT + c;
            float v = acc[r][c];
            if constexpr (FINAL) v += bias[col];
            t_out[(size_t)row * F + col] = v;
        }
    }
}

// Gather aggregation: one wave per dst node, lane = feature.
// agg[d] = relu(bias + dinv[d]^2 * t[d] + sum_e w_e * t[src_e])
// 8-wide edge batches: 8 independent gather loads in flight per batch.
__global__ __launch_bounds__(256)
void k_gather(const int* __restrict__ row_ptr, const int2* __restrict__ colw,
              const float* __restrict__ dinv, const float* __restrict__ bias,
              const float* __restrict__ t, float* __restrict__ agg, int N) {
    int gid  = blockIdx.x * blockDim.x + threadIdx.x;
    int d    = gid >> 6;
    int lane = threadIdx.x & 63;
    if (d >= N) return;

    int beg = row_ptr[d], end = row_ptr[d + 1];
    float dd  = dinv[d];
    float acc = bias[lane] + dd * dd * t[(size_t)d * 64 + lane];

    for (int base = beg; base < end; base += 64) {
        int nc = end - base;
        if (nc > 64) nc = 64;
        // inactive lanes carry weight 0 -> fma adds 0 * t[0]
        int2 cw = (lane < nc) ? colw[base + lane] : make_int2(0, 0);
        for (int j = 0; j < nc; j += 8) {
            int   s[8];
            float w[8];
#pragma unroll
            for (int k = 0; k < 8; ++k) {
                s[k] = __shfl(cw.x, j + k);
                w[k] = __int_as_float(__shfl(cw.y, j + k));
            }
            float v[8];
#pragma unroll
            for (int k = 0; k < 8; ++k)
                v[k] = t[(size_t)s[k] * 64 + lane];
#pragma unroll
            for (int k = 0; k < 8; ++k)
                acc = fmaf(w[k], v[k], acc);
        }
    }
    agg[(size_t)d * 64 + lane] = fmaxf(acc, 0.f);
}

extern "C" void kernel_launch(void* const* d_in, const int* in_sizes, int n_in,
                              void* d_out, int out_size, void* d_ws, size_t ws_size,
                              hipStream_t stream) {
    const float* x  = (const float*)d_in[0];
    const int*   ei = (const int*)d_in[1];
    const float* W1 = (const float*)d_in[2];
    const float* b1 = (const float*)d_in[3];
    const float* W2 = (const float*)d_in[4];
    const float* b2 = (const float*)d_in[5];
    const float* Wl = (const float*)d_in[6];
    const float* bl = (const float*)d_in[7];
    float*       out = (float*)d_out;

    const int N = in_sizes[0] / 64;
    const int E = in_sizes[1] / 2;
    const int* srcp = ei;
    const int* dstp = ei + E;

    char*  ws  = (char*)d_ws;
    size_t off = 0;
    auto alloc = [&](size_t bytes) -> void* {
        void* p = (void*)(ws + off);
        off += (bytes + 255) & ~(size_t)255;
        return p;
    };
    const int NB = (N + SCAN_EPB - 1) / SCAN_EPB;

    int*   cnt     = (int*)alloc((size_t)N * 4);
    int*   row_ptr = (int*)alloc((size_t)(N + 1) * 4);
    int*   cursor  = (int*)alloc((size_t)N * 4);
    int*   bsum    = (int*)alloc((size_t)NB * 4);
    float* dinv    = (float*)alloc((size_t)N * 4);
    int2*  colw    = (int2*)alloc((size_t)E * 8);
    float* t       = (float*)alloc((size_t)N * 64 * 4);
    float* agg1    = (float*)alloc((size_t)N * 64 * 4);
    float* agg2    = agg1;   // safe: agg1 dead once mm2 wrote t

    const int nb_n  = (N + 255) / 256;
    const int nb_e  = (E + 255) / 256;
    const int nb_mm = (N + 63) / 64;
    const int nb_g  = (int)(((size_t)N * 64 + 255) / 256);

    // --- CSR build ---
    k_zero_int<<<nb_n, 256, 0, stream>>>(cnt, N);
    k_hist<<<nb_e, 256, 0, stream>>>(dstp, cnt, E);
    k_scan1<<<NB, SCAN_TPB, 0, stream>>>(cnt, bsum, N);
    k_scan2<<<1, SCAN_TPB, 0, stream>>>(bsum, row_ptr, NB, N);
    k_scan3<<<NB, SCAN_TPB, 0, stream>>>(cnt, bsum, row_ptr, cursor, dinv, N);
    k_fill<<<nb_e, 256, 0, stream>>>(srcp, dstp, dinv, cursor, colw, E);

    // --- layer 1 ---
    k_mm<64, false><<<nb_mm, 256, 0, stream>>>(x, W1, nullptr, t, N);
    k_gather<<<nb_g, 256, 0, stream>>>(row_ptr, colw, dinv, b1, t, agg1, N);

    // --- layer 2 ---
    k_mm<64, false><<<nb_mm, 256, 0, stream>>>(agg1, W2, nullptr, t, N);
    k_gather<<<nb_g, 256, 0, stream>>>(row_ptr, colw, dinv, b2, t, agg2, N);

    // --- head ---
    k_mm<32, true><<<nb_mm, 256, 0, stream>>>(agg2, Wl, bl, out, N);
}

// Round 4
// 286.841 us; speedup vs baseline: 2.1977x; 1.0996x over previous
//
#include <hip/hip_runtime.h>
#include <math.h>

// ---------------------------------------------------------------------------
// GCN via on-device CSR build (fused hist+rank, atomic-free fill) +
// atomic-free gather aggregation (8-wide edge batches).
// out = (relu(Ahat@(relu(Ahat@(x@W1)+b1))@W2+b2)) @ Wl + bl
// Ahat = D^-1/2 (A+I) D^-1/2, deg = in-degree(dst) + 1.
// ---------------------------------------------------------------------------

#define SCAN_TPB 256
#define SCAN_EPB 1024   // 256 threads * 4 elems

__global__ void k_zero_int(int* p, int n) {
    int i = blockIdx.x * blockDim.x + threadIdx.x;
    if (i < n) p[i] = 0;
}

// hist + rank in one pass: rank[e] = position of edge e within its dst bucket.
// 4 edges per thread -> 4 independent atomics in flight.
__global__ void k_hist_rank(const int* __restrict__ dst, int* cnt,
                            int* __restrict__ rank, int E) {
    int t  = blockIdx.x * blockDim.x + threadIdx.x;
    int e0 = t * 4;
    if (e0 + 3 < E) {
        int4 d = *(const int4*)&dst[e0];
        int r0 = atomicAdd(&cnt[d.x], 1);
        int r1 = atomicAdd(&cnt[d.y], 1);
        int r2 = atomicAdd(&cnt[d.z], 1);
        int r3 = atomicAdd(&cnt[d.w], 1);
        *(int4*)&rank[e0] = make_int4(r0, r1, r2, r3);
    } else {
        for (int e = e0; e < E; ++e)
            rank[e] = atomicAdd(&cnt[dst[e]], 1);
    }
}

// pass 1: per-block sums of cnt (1024 elems/block)
__global__ __launch_bounds__(SCAN_TPB)
void k_scan1(const int* __restrict__ cnt, int* bsum, int N) {
    __shared__ int s[SCAN_TPB];
    int tid = threadIdx.x;
    int i0  = blockIdx.x * SCAN_EPB + tid * 4;
    int t = 0;
#pragma unroll
    for (int k = 0; k < 4; ++k) {
        int i = i0 + k;
        t += (i < N) ? cnt[i] : 0;
    }
    s[tid] = t;
    __syncthreads();
    for (int off = SCAN_TPB / 2; off > 0; off >>= 1) {
        if (tid < off) s[tid] += s[tid + off];
        __syncthreads();
    }
    if (tid == 0) bsum[blockIdx.x] = s[0];
}

// pass 2: exclusive scan of block sums (single block), total -> row_ptr[N]
__global__ __launch_bounds__(SCAN_TPB)
void k_scan2(int* bsum, int* row_ptr, int NB, int N) {
    __shared__ int s[SCAN_TPB];
    int tid = threadIdx.x;
    int v = (tid < NB) ? bsum[tid] : 0;
    s[tid] = v;
    __syncthreads();
    for (int off = 1; off < SCAN_TPB; off <<= 1) {
        int x = (tid >= off) ? s[tid - off] : 0;
        __syncthreads();
        s[tid] += x;
        __syncthreads();
    }
    if (tid < NB) bsum[tid] = s[tid] - v;       // exclusive
    if (tid == SCAN_TPB - 1) row_ptr[N] = s[SCAN_TPB - 1];  // total = E
}

// pass 3: full exclusive scan -> row_ptr; dinv = rsqrt(cnt+1)
__global__ __launch_bounds__(SCAN_TPB)
void k_scan3(const int* __restrict__ cnt, const int* __restrict__ bsum,
             int* row_ptr, float* dinv, int N) {
    __shared__ int s[SCAN_TPB];
    int tid = threadIdx.x;
    int i0  = blockIdx.x * SCAN_EPB + tid * 4;
    int v[4];
#pragma unroll
    for (int k = 0; k < 4; ++k) {
        int i = i0 + k;
        v[k] = (i < N) ? cnt[i] : 0;
    }
    int tsum = v[0] + v[1] + v[2] + v[3];
    s[tid] = tsum;
    __syncthreads();
    for (int off = 1; off < SCAN_TPB; off <<= 1) {
        int x = (tid >= off) ? s[tid - off] : 0;
        __syncthreads();
        s[tid] += x;
        __syncthreads();
    }
    int base = bsum[blockIdx.x] + (s[tid] - tsum);  // exclusive within grid
    int run = 0;
#pragma unroll
    for (int k = 0; k < 4; ++k) {
        int i = i0 + k;
        if (i < N) {
            row_ptr[i] = base + run;
            dinv[i]    = rsqrtf((float)(v[k] + 1));
        }
        run += v[k];
    }
}

// atomic-free bucket fill: colw[row_ptr[d] + rank[e]] = {src, dinv[s]*dinv[d]}
// 4 edges per thread -> all random loads/stores independent, issued together.
__global__ void k_fill(const int* __restrict__ src, const int* __restrict__ dst,
                       const int* __restrict__ rank,
                       const int* __restrict__ row_ptr,
                       const float* __restrict__ dinv,
                       int2* __restrict__ colw, int E) {
    int t  = blockIdx.x * blockDim.x + threadIdx.x;
    int e0 = t * 4;
    if (e0 + 3 < E) {
        int4 s4 = *(const int4*)&src[e0];
        int4 d4 = *(const int4*)&dst[e0];
        int4 r4 = *(const int4*)&rank[e0];
        int   sv[4] = {s4.x, s4.y, s4.z, s4.w};
        int   dv[4] = {d4.x, d4.y, d4.z, d4.w};
        int   rv[4] = {r4.x, r4.y, r4.z, r4.w};
        int   p[4];
        float ws[4], wd[4];
#pragma unroll
        for (int k = 0; k < 4; ++k) {
            p[k]  = row_ptr[dv[k]] + rv[k];
            ws[k] = dinv[sv[k]];
            wd[k] = dinv[dv[k]];
        }
#pragma unroll
        for (int k = 0; k < 4; ++k)
            colw[p[k]] = make_int2(sv[k], __float_as_int(ws[k] * wd[k]));
    } else {
        for (int e = e0; e < E; ++e) {
            int s = src[e], d = dst[e];
            colw[row_ptr[d] + rank[e]] =
                make_int2(s, __float_as_int(dinv[s] * dinv[d]));
        }
    }
}

// Dense GEMM: [n,64] @ [64,F], writes t_out = in@W (+bias if FINAL).
template <int F, bool FINAL>
__launch_bounds__(256)
__global__ void k_mm(const float* __restrict__ in, const float* __restrict__ W,
                     const float* __restrict__ bias,
                     float* __restrict__ t_out, int n) {
    __shared__ float in_s[64 * 68];
    __shared__ float w_s[64 * F];

    const int tid  = threadIdx.x;
    const int row0 = blockIdx.x * 64;

    for (int i4 = tid; i4 < (64 * F) / 4; i4 += 256)
        ((float4*)w_s)[i4] = ((const float4*)W)[i4];

    for (int idx = tid; idx < 64 * 16; idx += 256) {
        int r  = idx >> 4;
        int c4 = idx & 15;
        float4 v;
        if (row0 + r < n)
            v = *(const float4*)&in[(size_t)(row0 + r) * 64 + c4 * 4];
        else
            v = make_float4(0.f, 0.f, 0.f, 0.f);
        *(float4*)&in_s[r * 68 + c4 * 4] = v;
    }
    __syncthreads();

    constexpr int CPT = F / 16;
    const int tx = tid & 15;
    const int ty = tid >> 4;

    float acc[4][CPT];
#pragma unroll
    for (int r = 0; r < 4; ++r)
#pragma unroll
        for (int c = 0; c < CPT; ++c) acc[r][c] = 0.f;

#pragma unroll 4
    for (int k = 0; k < 64; ++k) {
        float b[CPT];
#pragma unroll
        for (int c = 0; c < CPT; ++c) b[c] = w_s[k * F + tx * CPT + c];
#pragma unroll
        for (int r = 0; r < 4; ++r) {
            float a = in_s[(ty * 4 + r) * 68 + k];
#pragma unroll
            for (int c = 0; c < CPT; ++c) acc[r][c] = fmaf(a, b[c], acc[r][c]);
        }
    }

#pragma unroll
    for (int r = 0; r < 4; ++r) {
        int row = row0 + ty * 4 + r;
        if (row >= n) continue;
#pragma unroll
        for (int c = 0; c < CPT; ++c) {
            int col = tx * CPT + c;
            float v = acc[r][c];
            if constexpr (FINAL) v += bias[col];
            t_out[(size_t)row * F + col] = v;
        }
    }
}

// Gather aggregation: one wave per dst node, lane = feature.
// agg[d] = relu(bias + dinv[d]^2 * t[d] + sum_e w_e * t[src_e])
// 8-wide edge batches: 8 independent gather loads in flight per batch.
__global__ __launch_bounds__(256)
void k_gather(const int* __restrict__ row_ptr, const int2* __restrict__ colw,
              const float* __restrict__ dinv, const float* __restrict__ bias,
              const float* __restrict__ t, float* __restrict__ agg, int N) {
    int gid  = blockIdx.x * blockDim.x + threadIdx.x;
    int d    = gid >> 6;
    int lane = threadIdx.x & 63;
    if (d >= N) return;

    int beg = row_ptr[d], end = row_ptr[d + 1];
    float dd  = dinv[d];
    float acc = bias[lane] + dd * dd * t[(size_t)d * 64 + lane];

    for (int base = beg; base < end; base += 64) {
        int nc = end - base;
        if (nc > 64) nc = 64;
        // inactive lanes carry weight 0 -> fma adds 0 * t[0]
        int2 cw = (lane < nc) ? colw[base + lane] : make_int2(0, 0);
        for (int j = 0; j < nc; j += 8) {
            int   s[8];
            float w[8];
#pragma unroll
            for (int k = 0; k < 8; ++k) {
                s[k] = __shfl(cw.x, j + k);
                w[k] = __int_as_float(__shfl(cw.y, j + k));
            }
            float v[8];
#pragma unroll
            for (int k = 0; k < 8; ++k)
                v[k] = t[(size_t)s[k] * 64 + lane];
#pragma unroll
            for (int k = 0; k < 8; ++k)
                acc = fmaf(w[k], v[k], acc);
        }
    }
    agg[(size_t)d * 64 + lane] = fmaxf(acc, 0.f);
}

extern "C" void kernel_launch(void* const* d_in, const int* in_sizes, int n_in,
                              void* d_out, int out_size, void* d_ws, size_t ws_size,
                              hipStream_t stream) {
    const float* x  = (const float*)d_in[0];
    const int*   ei = (const int*)d_in[1];
    const float* W1 = (const float*)d_in[2];
    const float* b1 = (const float*)d_in[3];
    const float* W2 = (const float*)d_in[4];
    const float* b2 = (const float*)d_in[5];
    const float* Wl = (const float*)d_in[6];
    const float* bl = (const float*)d_in[7];
    float*       out = (float*)d_out;

    const int N = in_sizes[0] / 64;
    const int E = in_sizes[1] / 2;
    const int* srcp = ei;
    const int* dstp = ei + E;

    char*  ws  = (char*)d_ws;
    size_t off = 0;
    auto alloc = [&](size_t bytes) -> void* {
        void* p = (void*)(ws + off);
        off += (bytes + 255) & ~(size_t)255;
        return p;
    };
    const int NB = (N + SCAN_EPB - 1) / SCAN_EPB;

    int*   cnt     = (int*)alloc((size_t)N * 4);
    int*   row_ptr = (int*)alloc((size_t)(N + 1) * 4);
    int*   rank    = (int*)alloc((size_t)E * 4);
    int*   bsum    = (int*)alloc((size_t)NB * 4);
    float* dinv    = (float*)alloc((size_t)N * 4);
    int2*  colw    = (int2*)alloc((size_t)E * 8);
    float* t       = (float*)alloc((size_t)N * 64 * 4);
    float* agg1    = (float*)alloc((size_t)N * 64 * 4);
    float* agg2    = agg1;   // safe: agg1 dead once mm2 wrote t

    const int nb_n  = (N + 255) / 256;
    const int nb_e4 = (E / 4 + 255) / 256 + 1;
    const int nb_mm = (N + 63) / 64;
    const int nb_g  = (int)(((size_t)N * 64 + 255) / 256);

    // --- CSR build ---
    k_zero_int<<<nb_n, 256, 0, stream>>>(cnt, N);
    k_hist_rank<<<nb_e4, 256, 0, stream>>>(dstp, cnt, rank, E);
    k_scan1<<<NB, SCAN_TPB, 0, stream>>>(cnt, bsum, N);
    k_scan2<<<1, SCAN_TPB, 0, stream>>>(bsum, row_ptr, NB, N);
    k_scan3<<<NB, SCAN_TPB, 0, stream>>>(cnt, bsum, row_ptr, dinv, N);
    k_fill<<<nb_e4, 256, 0, stream>>>(srcp, dstp, rank, row_ptr, dinv, colw, E);

    // --- layer 1 ---
    k_mm<64, false><<<nb_mm, 256, 0, stream>>>(x, W1, nullptr, t, N);
    k_gather<<<nb_g, 256, 0, stream>>>(row_ptr, colw, dinv, b1, t, agg1, N);

    // --- layer 2 ---
    k_mm<64, false><<<nb_mm, 256, 0, stream>>>(agg1, W2, nullptr, t, N);
    k_gather<<<nb_g, 256, 0, stream>>>(row_ptr, colw, dinv, b2, t, agg2, N);

    // --- head ---
    k_mm<32, true><<<nb_mm, 256, 0, stream>>>(agg2, Wl, bl, out, N);
}